// Round 3
// baseline (1138.157 us; speedup 1.0000x reference)
//
#include <hip/hip_runtime.h>
#include <hip/hip_bf16.h>
#include <math.h>

#define NN 50000
#define NE 800000
#define NEG_SLOPE 0.2f

// ---- workspace layout (f32-word offsets), peak 14,600,001 words = 58.4 MB --
//  [0      , 3.2M )  xl1b  bf16 N*128 (internal, always bf16)
//  [3.2M   , 6.4M )  xr1b  bf16 N*128      dies after escore1; then overlaid:
//     [3.2M , 3.45M)   xl2    f32 N*5
//     [3.45M, 3.7M )   xr2    f32 N*5
//     [3.7M , 4.5M )   logits2 f32 E
//     [4.5M , 4.75M)   acc2   f32 N*5
//     [4.75M, 4.8M )   mx2    u32 N
//     [4.8M , 4.85M)   den2   f32 N
//  [6.4M   , 8.0M )  logits1 f32 E*2
//  [8.0M   , 8.1M )  mx1   u32 N*2
//  [8.1M   , 8.2M )  den1  f32 N*2
//  [8.2M   , 14.6M)  acc1  f32 N*128
//  [14.6M]           flag  int (1 = inputs/outputs are bf16, 0 = f32)
// ----------------------------------------------------------------------------

// Dual-dtype load: device-sniffed flag picks interpretation (wave-uniform).
__device__ __forceinline__ float ldf(const void* p, long i, int isbf) {
    if (isbf) {
        unsigned short raw = ((const unsigned short*)p)[i];
        return __uint_as_float(((unsigned)raw) << 16);
    }
    return ((const float*)p)[i];
}

__device__ __forceinline__ float b2f(const __hip_bfloat16* p, long i) {
    return __bfloat162float(p[i]);
}

// Orderable-uint transform for float atomicMax (init 0 == identity).
__device__ __forceinline__ unsigned f2ord(float f) {
    unsigned u = __float_as_uint(f);
    return (u & 0x80000000u) ? ~u : (u | 0x80000000u);
}
__device__ __forceinline__ float ord2f(unsigned x) {
    return (x & 0x80000000u) ? __uint_as_float(x & 0x7fffffffu)
                             : __uint_as_float(~x);
}

// Decide input dtype: sample bf16 elements at EVEN indices of x. If buffer is
// truly bf16 these are actual N(0,1) values (sane). If buffer is f32 they are
// mantissa low-halves (random exponent -> mostly insane magnitudes).
__global__ void k_sniff(const void* x, int* flag) {
    __shared__ int cnt;
    if (threadIdx.x == 0) cnt = 0;
    __syncthreads();
    unsigned short raw = ((const unsigned short*)x)[threadIdx.x * 2];
    float v = __uint_as_float(((unsigned)raw) << 16);
    bool sane = isfinite(v) && fabsf(v) > 1e-5f && fabsf(v) < 1e3f;
    if (sane) atomicAdd(&cnt, 1);
    __syncthreads();
    if (threadIdx.x == 0) *flag = (cnt > 128) ? 1 : 0;
}

__global__ void k_init(float* __restrict__ z, int n) {
    int i = blockIdx.x * blockDim.x + threadIdx.x;
    if (i < n) z[i] = 0.f;
}

// xl1/xr1 = bf16(x @ W1l + b1l), bf16(x @ W1r + b1r)   [N,128] x [128,128]
__global__ __launch_bounds__(128) void k_lin1(
    const void* __restrict__ x,
    const void* __restrict__ Wl, const void* __restrict__ bl,
    const void* __restrict__ Wr, const void* __restrict__ br,
    __hip_bfloat16* __restrict__ xl, __hip_bfloat16* __restrict__ xr,
    const int* __restrict__ flag) {
    const int isbf = flag[0];
    __shared__ float xs[8][128];
    const int t = threadIdx.x;
    const long base = (long)blockIdx.x * 8;
    for (int r = 0; r < 8; r++) xs[r][t] = ldf(x, (base + r) * 128 + t, isbf);
    __syncthreads();
    float al[8], ar[8];
    const float blv = ldf(bl, t, isbf), brv = ldf(br, t, isbf);
#pragma unroll
    for (int r = 0; r < 8; r++) { al[r] = blv; ar[r] = brv; }
    for (int k = 0; k < 128; k++) {
        const float wl = ldf(Wl, k * 128 + t, isbf);
        const float wr = ldf(Wr, k * 128 + t, isbf);
#pragma unroll
        for (int r = 0; r < 8; r++) {
            al[r] = fmaf(xs[r][k], wl, al[r]);
            ar[r] = fmaf(xs[r][k], wr, ar[r]);
        }
    }
    for (int r = 0; r < 8; r++) {
        xl[(base + r) * 128 + t] = __float2bfloat16(al[r]);
        xr[(base + r) * 128 + t] = __float2bfloat16(ar[r]);
    }
}

// Layer-1 edge scores: 1 wave per edge, lane = channel (head0: c, head1: 64+c).
__global__ __launch_bounds__(256) void k_escore1(
    const int* __restrict__ ei, const void* __restrict__ ea,
    const __hip_bfloat16* __restrict__ xl, const __hip_bfloat16* __restrict__ xr,
    const void* __restrict__ We, const void* __restrict__ be,
    const void* __restrict__ att,
    float* __restrict__ logits, unsigned* __restrict__ mx,
    const int* __restrict__ flag) {
    const int isbf = flag[0];
    const int e = blockIdx.x * 4 + (threadIdx.x >> 6);
    if (e >= NE) return;
    const int lane = threadIdx.x & 63;
    const int s = ei[e], d = ei[NE + e];
    const float a = ldf(ea, e, isbf);
    float s0 = b2f(xl, (long)s * 128 + lane) + b2f(xr, (long)d * 128 + lane)
             + a * ldf(We, lane, isbf) + ldf(be, lane, isbf);
    float s1 = b2f(xl, (long)s * 128 + 64 + lane) + b2f(xr, (long)d * 128 + 64 + lane)
             + a * ldf(We, 64 + lane, isbf) + ldf(be, 64 + lane, isbf);
    s0 = s0 > 0.f ? s0 : NEG_SLOPE * s0;
    s1 = s1 > 0.f ? s1 : NEG_SLOPE * s1;
    float p0 = s0 * ldf(att, lane, isbf);        // att1[0][c]
    float p1 = s1 * ldf(att, 64 + lane, isbf);   // att1[1][c]
#pragma unroll
    for (int off = 32; off; off >>= 1) {
        p0 += __shfl_down(p0, off);
        p1 += __shfl_down(p1, off);
    }
    if (lane == 0) {
        logits[(long)e * 2]     = p0;
        logits[(long)e * 2 + 1] = p1;
        atomicMax(&mx[d * 2],     f2ord(p0));
        atomicMax(&mx[d * 2 + 1], f2ord(p1));
    }
}

__global__ void k_eexp1(const int* __restrict__ ei, float* __restrict__ logits,
                        const unsigned* __restrict__ mx, float* __restrict__ den) {
    const int e = blockIdx.x * blockDim.x + threadIdx.x;
    if (e >= NE) return;
    const int d = ei[NE + e];
    const float ex0 = expf(fminf(logits[(long)e * 2]     - ord2f(mx[d * 2]),     0.f));
    const float ex1 = expf(fminf(logits[(long)e * 2 + 1] - ord2f(mx[d * 2 + 1]), 0.f));
    logits[(long)e * 2]     = ex0;
    logits[(long)e * 2 + 1] = ex1;
    atomicAdd(&den[d * 2],     ex0);
    atomicAdd(&den[d * 2 + 1], ex1);
}

__global__ __launch_bounds__(256) void k_eacc1(
    const int* __restrict__ ei, const float* __restrict__ logits,
    const float* __restrict__ den, const __hip_bfloat16* __restrict__ xl,
    float* __restrict__ acc) {
    const int e = blockIdx.x * 4 + (threadIdx.x >> 6);
    if (e >= NE) return;
    const int lane = threadIdx.x & 63;
    const int s = ei[e], d = ei[NE + e];
    const float a0 = logits[(long)e * 2]     / fmaxf(den[d * 2],     1e-20f);
    const float a1 = logits[(long)e * 2 + 1] / fmaxf(den[d * 2 + 1], 1e-20f);
    atomicAdd(&acc[(long)d * 128 + lane],      a0 * b2f(xl, (long)s * 128 + lane));
    atomicAdd(&acc[(long)d * 128 + 64 + lane], a1 * b2f(xl, (long)s * 128 + 64 + lane));
}

__global__ void k_elu(float* __restrict__ h, const void* __restrict__ bias,
                      const int* __restrict__ flag) {
    const int isbf = flag[0];
    const int i = blockIdx.x * blockDim.x + threadIdx.x;
    if (i >= NN * 128) return;
    const float v = h[i] + ldf(bias, i & 127, isbf);
    h[i] = v > 0.f ? v : expm1f(v);
}

// Layer-2 linears: 1 wave per node, butterfly reduce 2x5 dot products (K=128).
__global__ __launch_bounds__(256) void k_lin2(
    const float* __restrict__ h,
    const void* __restrict__ Wl, const void* __restrict__ bl,
    const void* __restrict__ Wr, const void* __restrict__ br,
    float* __restrict__ xl2, float* __restrict__ xr2,
    const int* __restrict__ flag) {
    const int isbf = flag[0];
    const int n = blockIdx.x * 4 + (threadIdx.x >> 6);
    if (n >= NN) return;
    const int lane = threadIdx.x & 63;
    const float h0 = h[(long)n * 128 + lane];
    const float h1 = h[(long)n * 128 + 64 + lane];
    float pl[5], pr[5];
#pragma unroll
    for (int c = 0; c < 5; c++) {
        pl[c] = h0 * ldf(Wl, lane * 5 + c, isbf) + h1 * ldf(Wl, (64 + lane) * 5 + c, isbf);
        pr[c] = h0 * ldf(Wr, lane * 5 + c, isbf) + h1 * ldf(Wr, (64 + lane) * 5 + c, isbf);
    }
#pragma unroll
    for (int off = 32; off; off >>= 1) {
#pragma unroll
        for (int c = 0; c < 5; c++) {
            pl[c] += __shfl_xor(pl[c], off);
            pr[c] += __shfl_xor(pr[c], off);
        }
    }
    if (lane == 0) {
#pragma unroll
        for (int c = 0; c < 5; c++) {
            xl2[(long)n * 5 + c] = pl[c] + ldf(bl, c, isbf);
            xr2[(long)n * 5 + c] = pr[c] + ldf(br, c, isbf);
        }
    }
}

__global__ void k_escore2(
    const int* __restrict__ ei, const void* __restrict__ ea,
    const float* __restrict__ xl2, const float* __restrict__ xr2,
    const void* __restrict__ We, const void* __restrict__ be,
    const void* __restrict__ att,
    float* __restrict__ logits, unsigned* __restrict__ mx,
    const int* __restrict__ flag) {
    const int isbf = flag[0];
    const int e = blockIdx.x * blockDim.x + threadIdx.x;
    if (e >= NE) return;
    const int s = ei[e], d = ei[NE + e];
    const float a = ldf(ea, e, isbf);
    float l = 0.f;
#pragma unroll
    for (int c = 0; c < 5; c++) {
        float v = xl2[(long)s * 5 + c] + xr2[(long)d * 5 + c]
                + a * ldf(We, c, isbf) + ldf(be, c, isbf);
        v = v > 0.f ? v : NEG_SLOPE * v;
        l += v * ldf(att, c, isbf);
    }
    logits[e] = l;
    atomicMax(&mx[d], f2ord(l));
}

__global__ void k_eexp2(const int* __restrict__ ei, float* __restrict__ logits,
                        const unsigned* __restrict__ mx, float* __restrict__ den) {
    const int e = blockIdx.x * blockDim.x + threadIdx.x;
    if (e >= NE) return;
    const int d = ei[NE + e];
    const float ex = expf(fminf(logits[e] - ord2f(mx[d]), 0.f));
    logits[e] = ex;
    atomicAdd(&den[d], ex);
}

__global__ void k_eacc2(const int* __restrict__ ei, const float* __restrict__ logits,
                        const float* __restrict__ den, const float* __restrict__ xl2,
                        float* __restrict__ acc) {
    const int e = blockIdx.x * blockDim.x + threadIdx.x;
    if (e >= NE) return;
    const int s = ei[e], d = ei[NE + e];
    const float alpha = logits[e] / fmaxf(den[d], 1e-20f);
#pragma unroll
    for (int c = 0; c < 5; c++)
        atomicAdd(&acc[(long)d * 5 + c], alpha * xl2[(long)s * 5 + c]);
}

__global__ void k_final(const float* __restrict__ acc,
                        const void* __restrict__ bias,
                        void* __restrict__ out, const int* __restrict__ flag) {
    const int isbf = flag[0];
    const int i = blockIdx.x * blockDim.x + threadIdx.x;
    if (i >= NN * 5) return;
    const float v = acc[i] + ldf(bias, i % 5, isbf);
    if (isbf) ((__hip_bfloat16*)out)[i] = __float2bfloat16(v);
    else      ((float*)out)[i] = v;
}

extern "C" void kernel_launch(void* const* d_in, const int* in_sizes, int n_in,
                              void* d_out, int out_size, void* d_ws, size_t ws_size,
                              hipStream_t stream) {
    const void* x    = d_in[0];
    const int*  ei   = (const int*)d_in[1];
    const void* ea   = d_in[2];
    const void* W1l  = d_in[3];
    const void* b1l  = d_in[4];
    const void* W1r  = d_in[5];
    const void* b1r  = d_in[6];
    const void* W1e  = d_in[7];
    const void* b1e  = d_in[8];
    const void* att1 = d_in[9];
    const void* bias1= d_in[10];
    const void* W2l  = d_in[11];
    const void* b2l  = d_in[12];
    const void* W2r  = d_in[13];
    const void* b2r  = d_in[14];
    const void* W2e  = d_in[15];
    const void* b2e  = d_in[16];
    const void* att2 = d_in[17];
    const void* bias2= d_in[18];

    float* W = (float*)d_ws;
    __hip_bfloat16* xl1b = (__hip_bfloat16*)(W);              // [0, 3.2M)
    __hip_bfloat16* xr1b = (__hip_bfloat16*)(W + 3200000);    // [3.2M, 6.4M) dies @escore1
    float*    xl2     = W + 3200000;                          // overlays dead xr1b
    float*    xr2     = W + 3450000;
    float*    logits2 = W + 3700000;
    float*    acc2    = W + 4500000;
    unsigned* mx2     = (unsigned*)(W + 4750000);
    float*    den2    = W + 4800000;
    float*    logits1 = W + 6400000;                          // [6.4M, 8.0M)
    unsigned* mx1     = (unsigned*)(W + 8000000);             // [8.0M, 8.1M)
    float*    den1    = W + 8100000;                          // [8.1M, 8.2M)
    float*    acc1    = W + 8200000;                          // [8.2M, 14.6M)
    int*      flag    = (int*)(W + 14600000);
    // peak: 14,600,001 words = 58.4 MB

    k_sniff<<<1, 256, 0, stream>>>(x, flag);

    // Layer 1
    k_init<<<(200000 + 255) / 256, 256, 0, stream>>>((float*)mx1, 200000); // mx1+den1
    k_lin1<<<NN / 8, 128, 0, stream>>>(x, W1l, b1l, W1r, b1r, xl1b, xr1b, flag);
    k_escore1<<<NE / 4, 256, 0, stream>>>(ei, ea, xl1b, xr1b, W1e, b1e, att1, logits1, mx1, flag);
    k_eexp1<<<(NE + 255) / 256, 256, 0, stream>>>(ei, logits1, mx1, den1);
    k_init<<<(NN * 128 + 255) / 256, 256, 0, stream>>>(acc1, NN * 128);
    k_init<<<(350000 + 255) / 256, 256, 0, stream>>>(acc2, 350000);       // acc2+mx2+den2
    k_eacc1<<<NE / 4, 256, 0, stream>>>(ei, logits1, den1, xl1b, acc1);
    k_elu<<<(NN * 128 + 255) / 256, 256, 0, stream>>>(acc1, bias1, flag);

    // Layer 2
    k_lin2<<<(NN + 3) / 4, 256, 0, stream>>>(acc1, W2l, b2l, W2r, b2r, xl2, xr2, flag);
    k_escore2<<<(NE + 255) / 256, 256, 0, stream>>>(ei, ea, xl2, xr2, W2e, b2e, att2, logits2, mx2, flag);
    k_eexp2<<<(NE + 255) / 256, 256, 0, stream>>>(ei, logits2, mx2, den2);
    k_eacc2<<<(NE + 255) / 256, 256, 0, stream>>>(ei, logits2, den2, xl2, acc2);
    k_final<<<(NN * 5 + 255) / 256, 256, 0, stream>>>(acc2, bias2, d_out, flag);
}

// Round 4
// 589.634 us; speedup vs baseline: 1.9303x; 1.9303x over previous
//
#include <hip/hip_runtime.h>
#include <hip/hip_bf16.h>
#include <math.h>

#define NN 50000
#define NE 800000
#define NEG_SLOPE 0.2f

// ---- workspace layout (f32-word offsets), peak ~11.82M words = 47.3 MB -----
//  [0]                flag (int: 1 = external bufs bf16, 0 = f32)
//  [1000  , 51001 )   row_ptr  u32 NN+1
//  [60000 , 110000)   cnt/cursor u32 NN   (counts, then scatter cursor)
//  [120000, 920000)   sorted_src i32 NE
//  [920000,1720000)   sorted_ea  f32 NE
//  [1720000,4920000)  xl1b  bf16 N*128 (stored as uint pairs)
//  [4920000,8120000)  xr1b  bf16 N*128
//  [8120000,11320000) hb    bf16 N*128 (post-ELU hidden)
//  [11320000,11570000) xl2  f32 N*5
//  [11570000,11820000) xr2  f32 N*5
// ----------------------------------------------------------------------------

// Dual-dtype scalar load (flag is wave-uniform).
__device__ __forceinline__ float ldf(const void* p, long i, int isbf) {
    if (isbf) {
        unsigned short raw = ((const unsigned short*)p)[i];
        return __uint_as_float(((unsigned)raw) << 16);
    }
    return ((const float*)p)[i];
}

// Load element pair (2*i2, 2*i2+1) as float2.
__device__ __forceinline__ float2 ldf2(const void* p, long i2, int isbf) {
    if (isbf) {
        unsigned raw = ((const unsigned*)p)[i2];
        return make_float2(__uint_as_float(raw << 16),
                           __uint_as_float(raw & 0xffff0000u));
    }
    return ((const float2*)p)[i2];
}

__device__ __forceinline__ unsigned packbf(float a, float b) {
    __hip_bfloat16 ha = __float2bfloat16(a), hb = __float2bfloat16(b);
    unsigned short ua, ub;
    __builtin_memcpy(&ua, &ha, 2);
    __builtin_memcpy(&ub, &hb, 2);
    return (unsigned)ua | ((unsigned)ub << 16);
}

// Input dtype sniff: bf16 elements at even indices of x are sane N(0,1) values
// iff the buffer really is bf16.
__global__ void k_sniff(const void* x, int* flag) {
    __shared__ int cnt;
    if (threadIdx.x == 0) cnt = 0;
    __syncthreads();
    unsigned short raw = ((const unsigned short*)x)[threadIdx.x * 2];
    float v = __uint_as_float(((unsigned)raw) << 16);
    bool sane = isfinite(v) && fabsf(v) > 1e-5f && fabsf(v) < 1e3f;
    if (sane) atomicAdd(&cnt, 1);
    __syncthreads();
    if (threadIdx.x == 0) *flag = (cnt > 128) ? 1 : 0;
}

__global__ void k_init(unsigned* __restrict__ z, int n) {
    int i = blockIdx.x * blockDim.x + threadIdx.x;
    if (i < n) z[i] = 0u;
}

__global__ void k_hist(const int* __restrict__ ei, unsigned* __restrict__ cnt) {
    int e = blockIdx.x * blockDim.x + threadIdx.x;
    if (e < NE) atomicAdd(&cnt[ei[NE + e]], 1u);
}

// Single-block exclusive scan of cnt[0..NN) -> row_ptr, cursor (cnt overwritten).
__global__ __launch_bounds__(1024) void k_scan(unsigned* cnt_cursor,
                                               unsigned* row_ptr) {
    __shared__ unsigned ts[1024];
    const int t = threadIdx.x;
    const int CH = (NN + 1023) / 1024;  // 49
    const int lo = t * CH, hi = (lo + CH < NN) ? lo + CH : NN;
    unsigned s = 0;
    for (int i = lo; i < hi; i++) s += cnt_cursor[i];
    ts[t] = s;
    __syncthreads();
    for (int off = 1; off < 1024; off <<= 1) {
        unsigned v = (t >= off) ? ts[t - off] : 0u;
        __syncthreads();
        if (t >= off) ts[t] += v;
        __syncthreads();
    }
    unsigned p = (t > 0) ? ts[t - 1] : 0u;
    for (int i = lo; i < hi; i++) {
        unsigned c = cnt_cursor[i];
        row_ptr[i] = p;
        cnt_cursor[i] = p;  // becomes scatter cursor
        p += c;
    }
    if (hi == NN) row_ptr[NN] = p;  // == NE
}

__global__ void k_scatter(const int* __restrict__ ei, const void* __restrict__ ea,
                          unsigned* __restrict__ cursor,
                          int* __restrict__ ssrc, float* __restrict__ sea,
                          const int* __restrict__ flag) {
    const int isbf = flag[0];
    int e = blockIdx.x * blockDim.x + threadIdx.x;
    if (e >= NE) return;
    int d = ei[NE + e];
    unsigned pos = atomicAdd(&cursor[d], 1u);
    ssrc[pos] = ei[e];
    sea[pos] = ldf(ea, e, isbf);
}

// xl1b/xr1b = bf16(x @ W1l + b1l), bf16(x @ W1r + b1r).  16 rows/block.
__global__ __launch_bounds__(256) void k_lin1(
    const void* __restrict__ x,
    const void* __restrict__ Wl, const void* __restrict__ bl,
    const void* __restrict__ Wr, const void* __restrict__ br,
    unsigned* __restrict__ xl, unsigned* __restrict__ xr,
    const int* __restrict__ flag) {
    const int isbf = flag[0];
    __shared__ float xs[16][128];
    const int t = threadIdx.x;
    const long rowbase = (long)blockIdx.x * 16;
    if (isbf) {
        const unsigned* xp = (const unsigned*)x + rowbase * 64;
#pragma unroll
        for (int k = 0; k < 4; k++) {
            unsigned raw = xp[t + k * 256];
            int idx = (t + k * 256) * 2;
            xs[idx >> 7][idx & 127]       = __uint_as_float(raw << 16);
            xs[idx >> 7][(idx & 127) + 1] = __uint_as_float(raw & 0xffff0000u);
        }
    } else {
        const float* xp = (const float*)x + rowbase * 128;
#pragma unroll
        for (int k = 0; k < 8; k++) {
            int idx = t + k * 256;
            xs[idx >> 7][idx & 127] = xp[idx];
        }
    }
    __syncthreads();
    const int c2 = t & 63;   // cols 2c2, 2c2+1
    const int rg = t >> 6;   // rows rg*4 .. rg*4+3 (wave-uniform)
    const float2 blv = ldf2(bl, c2, isbf), brv = ldf2(br, c2, isbf);
    float al0[4], al1[4], ar0[4], ar1[4];
#pragma unroll
    for (int j = 0; j < 4; j++) {
        al0[j] = blv.x; al1[j] = blv.y; ar0[j] = brv.x; ar1[j] = brv.y;
    }
    for (int k = 0; k < 128; k += 4) {
#pragma unroll
        for (int kk = 0; kk < 4; kk++) {
            const float2 wl = ldf2(Wl, (k + kk) * 64 + c2, isbf);
            const float2 wr = ldf2(Wr, (k + kk) * 64 + c2, isbf);
#pragma unroll
            for (int j = 0; j < 4; j++) {
                const float xv = xs[rg * 4 + j][k + kk];
                al0[j] = fmaf(xv, wl.x, al0[j]);
                al1[j] = fmaf(xv, wl.y, al1[j]);
                ar0[j] = fmaf(xv, wr.x, ar0[j]);
                ar1[j] = fmaf(xv, wr.y, ar1[j]);
            }
        }
    }
#pragma unroll
    for (int j = 0; j < 4; j++) {
        const long row = rowbase + rg * 4 + j;
        xl[row * 64 + c2] = packbf(al0[j], al1[j]);
        xr[row * 64 + c2] = packbf(ar0[j], ar1[j]);
    }
}

// Fused layer-1 attention: one wave per dst node, online softmax, epilogue
// bias+ELU. Lane holds channels 2*lane, 2*lane+1 (lanes 0..31 = head0).
__global__ __launch_bounds__(256) void k_attn1(
    const unsigned* __restrict__ rp, const int* __restrict__ ssrc,
    const float* __restrict__ sea,
    const unsigned* __restrict__ xl, const unsigned* __restrict__ xr,
    const void* __restrict__ We, const void* __restrict__ be,
    const void* __restrict__ att, const void* __restrict__ bias,
    unsigned* __restrict__ hb, const int* __restrict__ flag) {
    const int isbf = flag[0];
    const int n = blockIdx.x * 4 + (threadIdx.x >> 6);
    if (n >= NN) return;
    const int lane = threadIdx.x & 63;
    const unsigned rraw = xr[(long)n * 64 + lane];
    const float xr0 = __uint_as_float(rraw << 16);
    const float xr1 = __uint_as_float(rraw & 0xffff0000u);
    const float2 wev = ldf2(We, lane, isbf);
    const float2 bev = ldf2(be, lane, isbf);
    const float2 atv = ldf2(att, lane, isbf);
    float m = -INFINITY, l = 0.f, a0 = 0.f, a1 = 0.f;
    const int beg = rp[n], end = rp[n + 1];
    for (int i = beg; i < end; i++) {
        const int s = ssrc[i];
        const float a = sea[i];
        const unsigned raw = xl[(long)s * 64 + lane];
        const float x0 = __uint_as_float(raw << 16);
        const float x1 = __uint_as_float(raw & 0xffff0000u);
        float t0 = x0 + xr0 + fmaf(a, wev.x, bev.x);
        float t1 = x1 + xr1 + fmaf(a, wev.y, bev.y);
        t0 = t0 > 0.f ? t0 : NEG_SLOPE * t0;
        t1 = t1 > 0.f ? t1 : NEG_SLOPE * t1;
        float p = fmaf(t0, atv.x, t1 * atv.y);
#pragma unroll
        for (int off = 1; off <= 16; off <<= 1) p += __shfl_xor(p, off);
        // lanes 0..31 now hold head-0 logit, lanes 32..63 head-1 logit
        const float mn = fmaxf(m, p);
        const float sc = __expf(m - mn);
        const float w  = __expf(p - mn);
        l  = fmaf(l,  sc, w);
        a0 = fmaf(a0, sc, w * x0);
        a1 = fmaf(a1, sc, w * x1);
        m = mn;
    }
    const float inv = 1.f / fmaxf(l, 1e-20f);
    const float2 bsv = ldf2(bias, lane, isbf);
    float h0 = fmaf(a0, inv, bsv.x);
    float h1 = fmaf(a1, inv, bsv.y);
    h0 = h0 > 0.f ? h0 : expm1f(h0);
    h1 = h1 > 0.f ? h1 : expm1f(h1);
    hb[(long)n * 64 + lane] = packbf(h0, h1);
}

// Layer-2 linears: 1 wave per node, butterfly reduce 2x5 dots (K=128).
__global__ __launch_bounds__(256) void k_lin2(
    const unsigned* __restrict__ hb,
    const void* __restrict__ Wl, const void* __restrict__ bl,
    const void* __restrict__ Wr, const void* __restrict__ br,
    float* __restrict__ xl2, float* __restrict__ xr2,
    const int* __restrict__ flag) {
    const int isbf = flag[0];
    const int n = blockIdx.x * 4 + (threadIdx.x >> 6);
    if (n >= NN) return;
    const int lane = threadIdx.x & 63;
    const unsigned raw = hb[(long)n * 64 + lane];
    const float h0 = __uint_as_float(raw << 16);
    const float h1 = __uint_as_float(raw & 0xffff0000u);
    float pl[5], pr[5];
#pragma unroll
    for (int c = 0; c < 5; c++) {
        pl[c] = h0 * ldf(Wl, (2 * lane) * 5 + c, isbf)
              + h1 * ldf(Wl, (2 * lane + 1) * 5 + c, isbf);
        pr[c] = h0 * ldf(Wr, (2 * lane) * 5 + c, isbf)
              + h1 * ldf(Wr, (2 * lane + 1) * 5 + c, isbf);
    }
#pragma unroll
    for (int off = 1; off <= 32; off <<= 1) {
#pragma unroll
        for (int c = 0; c < 5; c++) {
            pl[c] += __shfl_xor(pl[c], off);
            pr[c] += __shfl_xor(pr[c], off);
        }
    }
    if (lane == 0) {
#pragma unroll
        for (int c = 0; c < 5; c++) {
            xl2[(long)n * 5 + c] = pl[c] + ldf(bl, c, isbf);
            xr2[(long)n * 5 + c] = pr[c] + ldf(br, c, isbf);
        }
    }
}

// Fused layer-2 attention: one wave per dst node, lane-per-edge chunks,
// online softmax across chunks; writes final output (+bias2).
__global__ __launch_bounds__(256) void k_attn2(
    const unsigned* __restrict__ rp, const int* __restrict__ ssrc,
    const float* __restrict__ sea,
    const float* __restrict__ xl2, const float* __restrict__ xr2,
    const void* __restrict__ We, const void* __restrict__ be,
    const void* __restrict__ att, const void* __restrict__ bias,
    void* __restrict__ out, const int* __restrict__ flag) {
    const int isbf = flag[0];
    const int n = blockIdx.x * 4 + (threadIdx.x >> 6);
    if (n >= NN) return;
    const int lane = threadIdx.x & 63;
    float xrv[5], wev[5], bev[5], atv[5];
#pragma unroll
    for (int c = 0; c < 5; c++) {
        xrv[c] = xr2[(long)n * 5 + c];
        wev[c] = ldf(We, c, isbf);
        bev[c] = ldf(be, c, isbf);
        atv[c] = ldf(att, c, isbf);
    }
    float m = -INFINITY, l = 0.f, acc[5] = {0.f, 0.f, 0.f, 0.f, 0.f};
    const int beg = rp[n], end = rp[n + 1];
    for (int chunk = beg; chunk < end; chunk += 64) {
        const int idx = chunk + lane;
        const bool active = idx < end;
        float p = -INFINITY;
        float xls[5] = {0.f, 0.f, 0.f, 0.f, 0.f};
        if (active) {
            const int s = ssrc[idx];
            const float a = sea[idx];
            p = 0.f;
#pragma unroll
            for (int c = 0; c < 5; c++) {
                xls[c] = xl2[(long)s * 5 + c];
                float v = xls[c] + xrv[c] + fmaf(a, wev[c], bev[c]);
                v = v > 0.f ? v : NEG_SLOPE * v;
                p = fmaf(v, atv[c], p);
            }
        }
        float pm = p;
#pragma unroll
        for (int off = 1; off <= 32; off <<= 1) pm = fmaxf(pm, __shfl_xor(pm, off));
        const float mn = fmaxf(m, pm);
        const float sc = __expf(m - mn);
        float w = active ? __expf(p - mn) : 0.f;
        float sw = w;
        float sv[5];
#pragma unroll
        for (int c = 0; c < 5; c++) sv[c] = w * xls[c];
#pragma unroll
        for (int off = 1; off <= 32; off <<= 1) {
            sw += __shfl_xor(sw, off);
#pragma unroll
            for (int c = 0; c < 5; c++) sv[c] += __shfl_xor(sv[c], off);
        }
        l = fmaf(l, sc, sw);
#pragma unroll
        for (int c = 0; c < 5; c++) acc[c] = fmaf(acc[c], sc, sv[c]);
        m = mn;
    }
    if (lane == 0) {
        const float inv = 1.f / fmaxf(l, 1e-20f);
#pragma unroll
        for (int c = 0; c < 5; c++) {
            const float v = fmaf(acc[c], inv, ldf(bias, c, isbf));
            if (isbf) ((__hip_bfloat16*)out)[(long)n * 5 + c] = __float2bfloat16(v);
            else      ((float*)out)[(long)n * 5 + c] = v;
        }
    }
}

extern "C" void kernel_launch(void* const* d_in, const int* in_sizes, int n_in,
                              void* d_out, int out_size, void* d_ws, size_t ws_size,
                              hipStream_t stream) {
    const void* x    = d_in[0];
    const int*  ei   = (const int*)d_in[1];
    const void* ea   = d_in[2];
    const void* W1l  = d_in[3];
    const void* b1l  = d_in[4];
    const void* W1r  = d_in[5];
    const void* b1r  = d_in[6];
    const void* W1e  = d_in[7];
    const void* b1e  = d_in[8];
    const void* att1 = d_in[9];
    const void* bias1= d_in[10];
    const void* W2l  = d_in[11];
    const void* b2l  = d_in[12];
    const void* W2r  = d_in[13];
    const void* b2r  = d_in[14];
    const void* W2e  = d_in[15];
    const void* b2e  = d_in[16];
    const void* att2 = d_in[17];
    const void* bias2= d_in[18];

    float* W = (float*)d_ws;
    int*      flag    = (int*)W;
    unsigned* row_ptr = (unsigned*)(W + 1000);      // NN+1
    unsigned* cursor  = (unsigned*)(W + 60000);     // NN (counts -> cursor)
    int*      ssrc    = (int*)(W + 120000);         // NE
    float*    sea     = W + 920000;                 // NE
    unsigned* xl1b    = (unsigned*)(W + 1720000);   // N*64 uints
    unsigned* xr1b    = (unsigned*)(W + 4920000);
    unsigned* hb      = (unsigned*)(W + 8120000);
    float*    xl2     = W + 11320000;               // N*5
    float*    xr2     = W + 11570000;               // N*5

    k_sniff<<<1, 256, 0, stream>>>(x, flag);

    // CSR build (dst-sorted edges)
    k_init<<<(NN + 255) / 256, 256, 0, stream>>>(cursor, NN);
    k_hist<<<(NE + 255) / 256, 256, 0, stream>>>(ei, cursor);
    k_scan<<<1, 1024, 0, stream>>>(cursor, row_ptr);
    k_scatter<<<(NE + 255) / 256, 256, 0, stream>>>(ei, ea, cursor, ssrc, sea, flag);

    // Layer 1
    k_lin1<<<NN / 16, 256, 0, stream>>>(x, W1l, b1l, W1r, b1r, xl1b, xr1b, flag);
    k_attn1<<<(NN + 3) / 4, 256, 0, stream>>>(row_ptr, ssrc, sea, xl1b, xr1b,
                                              W1e, b1e, att1, bias1, hb, flag);
    // Layer 2
    k_lin2<<<(NN + 3) / 4, 256, 0, stream>>>(hb, W2l, b2l, W2r, b2r, xl2, xr2, flag);
    k_attn2<<<(NN + 3) / 4, 256, 0, stream>>>(row_ptr, ssrc, sea, xl2, xr2,
                                              W2e, b2e, att2, bias2, d_out, flag);
}

// Round 5
// 461.813 us; speedup vs baseline: 2.4645x; 1.2768x over previous
//
#include <hip/hip_runtime.h>
#include <hip/hip_bf16.h>
#include <math.h>

#define NN 50000
#define NE 800000
#define NEG_SLOPE 0.2f

typedef __attribute__((ext_vector_type(8))) short bf16x8;
typedef __attribute__((ext_vector_type(4))) float f32x4;

// ---- workspace layout (f32-word offsets), peak 8.7M words = 34.8 MB --------
//  [0]                 flag (int: 1 = external bufs bf16, 0 = f32)
//  [1000  , 51001 )    row_ptr u32 NN+1
//  [60000 , 110000)    cnt/cursor u32 NN
//  [120000, 920000)    sorted_src i32 NE
//  [920000, 1720000)   sorted_ea  f32 NE
//  [1720000, 4920000)  xl1b bf16 N*128
//  [4920000, 8120000)  xr1b bf16 N*128
//  [8120000, 8136384)  bfrag bf16 32768 (W1l|W1r in MFMA B-fragment order)
//  [8200000, 8450000)  xl2 f32 N*5
//  [8450000, 8700000)  xr2 f32 N*5
// ----------------------------------------------------------------------------

__device__ __forceinline__ float ldf(const void* p, long i, int isbf) {
    if (isbf) {
        unsigned short raw = ((const unsigned short*)p)[i];
        return __uint_as_float(((unsigned)raw) << 16);
    }
    return ((const float*)p)[i];
}

__device__ __forceinline__ float2 ldf2(const void* p, long i2, int isbf) {
    if (isbf) {
        unsigned raw = ((const unsigned*)p)[i2];
        return make_float2(__uint_as_float(raw << 16),
                           __uint_as_float(raw & 0xffff0000u));
    }
    return ((const float2*)p)[i2];
}

__device__ __forceinline__ short f2bs(float f) {
    __hip_bfloat16 h = __float2bfloat16(f);
    short s; __builtin_memcpy(&s, &h, 2); return s;
}
__device__ __forceinline__ unsigned short f2bu(float f) {
    __hip_bfloat16 h = __float2bfloat16(f);
    unsigned short s; __builtin_memcpy(&s, &h, 2); return s;
}

// Input dtype sniff (bf16 halves at even indices are sane iff buffer is bf16).
__global__ void k_sniff(const void* x, int* flag) {
    __shared__ int cnt;
    if (threadIdx.x == 0) cnt = 0;
    __syncthreads();
    unsigned short raw = ((const unsigned short*)x)[threadIdx.x * 2];
    float v = __uint_as_float(((unsigned)raw) << 16);
    bool sane = isfinite(v) && fabsf(v) > 1e-5f && fabsf(v) < 1e3f;
    if (sane) atomicAdd(&cnt, 1);
    __syncthreads();
    if (threadIdx.x == 0) *flag = (cnt > 128) ? 1 : 0;
}

__global__ void k_init(unsigned* __restrict__ z, int n) {
    int i = blockIdx.x * blockDim.x + threadIdx.x;
    if (i < n) z[i] = 0u;
}

__global__ void k_hist(const int* __restrict__ ei, unsigned* __restrict__ cnt) {
    int e = blockIdx.x * blockDim.x + threadIdx.x;
    if (e < NE) atomicAdd(&cnt[ei[NE + e]], 1u);
}

__global__ __launch_bounds__(1024) void k_scan(unsigned* cnt_cursor,
                                               unsigned* row_ptr) {
    __shared__ unsigned ts[1024];
    const int t = threadIdx.x;
    const int CH = (NN + 1023) / 1024;
    const int lo = t * CH, hi = (lo + CH < NN) ? lo + CH : NN;
    unsigned s = 0;
    for (int i = lo; i < hi; i++) s += cnt_cursor[i];
    ts[t] = s;
    __syncthreads();
    for (int off = 1; off < 1024; off <<= 1) {
        unsigned v = (t >= off) ? ts[t - off] : 0u;
        __syncthreads();
        if (t >= off) ts[t] += v;
        __syncthreads();
    }
    unsigned p = (t > 0) ? ts[t - 1] : 0u;
    for (int i = lo; i < hi; i++) {
        unsigned c = cnt_cursor[i];
        row_ptr[i] = p;
        cnt_cursor[i] = p;
        p += c;
    }
    if (hi == NN) row_ptr[NN] = p;
}

__global__ void k_scatter(const int* __restrict__ ei, const void* __restrict__ ea,
                          unsigned* __restrict__ cursor,
                          int* __restrict__ ssrc, float* __restrict__ sea,
                          const int* __restrict__ flag) {
    const int isbf = flag[0];
    int e = blockIdx.x * blockDim.x + threadIdx.x;
    if (e >= NE) return;
    int d = ei[NE + e];
    unsigned pos = atomicAdd(&cursor[d], 1u);
    ssrc[pos] = ei[e];
    sea[pos] = ldf(ea, e, isbf);
}

// Pre-swizzle W = [W1l | W1r] (128K x 256N) into MFMA B-fragment order:
// bfrag[((nt*4+ks)*64+lane)*8+j] = W[k=ks*32+(lane>>4)*8+j][n=nt*16+(lane&15)]
__global__ void k_wprep(const void* __restrict__ Wl, const void* __restrict__ Wr,
                        unsigned short* __restrict__ bfrag,
                        const int* __restrict__ flag) {
    const int isbf = flag[0];
    int idx = blockIdx.x * blockDim.x + threadIdx.x;  // 0..32767
    int j = idx & 7, lane = (idx >> 3) & 63, ks = (idx >> 9) & 3, nt = idx >> 11;
    int k = ks * 32 + (lane >> 4) * 8 + j;
    int n = nt * 16 + (lane & 15);
    float v = (n < 128) ? ldf(Wl, (long)k * 128 + n, isbf)
                        : ldf(Wr, (long)k * 128 + (n - 128), isbf);
    bfrag[idx] = f2bu(v);
}

// MFMA GEMM: [xl1b | xr1b] = bf16(x @ [W1l|W1r] + [b1l|b1r]).
// Block = 16 rows x 256 cols; 4 waves, each wave 4 n-tiles, K=128 (4 MFMA).
__global__ __launch_bounds__(256) void k_lin1(
    const void* __restrict__ x, const unsigned short* __restrict__ bfrag,
    const void* __restrict__ bl, const void* __restrict__ br,
    unsigned short* __restrict__ xl, unsigned short* __restrict__ xr,
    const int* __restrict__ flag) {
    const int isbf = flag[0];
    const int wave = threadIdx.x >> 6, lane = threadIdx.x & 63;
    const int mrow = lane & 15, quad = lane >> 4;
    const long mbase = (long)blockIdx.x * 16;
    bf16x8 afrag[4];
    if (isbf) {
        const unsigned short* xp = (const unsigned short*)x
                                 + (mbase + mrow) * 128 + quad * 8;
#pragma unroll
        for (int ks = 0; ks < 4; ks++)
            afrag[ks] = *(const bf16x8*)(xp + ks * 32);
    } else {
        const float* xp = (const float*)x + (mbase + mrow) * 128 + quad * 8;
#pragma unroll
        for (int ks = 0; ks < 4; ks++) {
            const float4 u0 = *(const float4*)(xp + ks * 32);
            const float4 u1 = *(const float4*)(xp + ks * 32 + 4);
            bf16x8 a;
            a[0] = f2bs(u0.x); a[1] = f2bs(u0.y); a[2] = f2bs(u0.z); a[3] = f2bs(u0.w);
            a[4] = f2bs(u1.x); a[5] = f2bs(u1.y); a[6] = f2bs(u1.z); a[7] = f2bs(u1.w);
            afrag[ks] = a;
        }
    }
#pragma unroll
    for (int q = 0; q < 4; q++) {
        const int nt = wave * 4 + q;
        f32x4 acc = {0.f, 0.f, 0.f, 0.f};
#pragma unroll
        for (int ks = 0; ks < 4; ks++) {
            const bf16x8 bfr = *(const bf16x8*)(bfrag + ((nt * 4 + ks) * 64 + lane) * 8);
            acc = __builtin_amdgcn_mfma_f32_16x16x32_bf16(afrag[ks], bfr, acc, 0, 0, 0);
        }
        const int ng = nt * 16 + (lane & 15);
        const float bv = (ng < 128) ? ldf(bl, ng, isbf) : ldf(br, ng - 128, isbf);
        unsigned short* dst = (ng < 128) ? xl : xr;
        const int col = ng & 127;
#pragma unroll
        for (int reg = 0; reg < 4; reg++) {
            const long row = mbase + quad * 4 + reg;
            dst[row * 128 + col] = f2bu(acc[reg] + bv);
        }
    }
}

// Fused layer-1 attention + bias+ELU + layer-2 linears.
// One wave per dst node; lane holds channels 2*lane, 2*lane+1 (lanes 0..31 = head0).
// Two independent online-softmax chains (even/odd edges) for ILP.
__global__ __launch_bounds__(256) void k_attn1(
    const unsigned* __restrict__ rp, const int* __restrict__ ssrc,
    const float* __restrict__ sea,
    const unsigned* __restrict__ xl, const unsigned* __restrict__ xr,
    const void* __restrict__ We, const void* __restrict__ be,
    const void* __restrict__ att, const void* __restrict__ bias,
    const void* __restrict__ W2l, const void* __restrict__ b2l,
    const void* __restrict__ W2r, const void* __restrict__ b2r,
    float* __restrict__ xl2, float* __restrict__ xr2,
    const int* __restrict__ flag) {
    const int isbf = flag[0];
    const int n = blockIdx.x * 4 + (threadIdx.x >> 6);
    if (n >= NN) return;
    const int lane = threadIdx.x & 63;
    const unsigned rraw = xr[(long)n * 64 + lane];
    const float xr0 = __uint_as_float(rraw << 16);
    const float xr1 = __uint_as_float(rraw & 0xffff0000u);
    const float2 wev = ldf2(We, lane, isbf);
    const float2 bev = ldf2(be, lane, isbf);
    const float2 atv = ldf2(att, lane, isbf);
    float mA = -INFINITY, lA = 0.f, aA0 = 0.f, aA1 = 0.f;
    float mB = -INFINITY, lB = 0.f, aB0 = 0.f, aB1 = 0.f;
    const int beg = rp[n], end = rp[n + 1];
    int i = beg;
    for (; i + 1 < end; i += 2) {
        const int sA = ssrc[i], sB = ssrc[i + 1];
        const float eA = sea[i], eB = sea[i + 1];
        const unsigned rwA = xl[(long)sA * 64 + lane];
        const unsigned rwB = xl[(long)sB * 64 + lane];
        const float xA0 = __uint_as_float(rwA << 16);
        const float xA1 = __uint_as_float(rwA & 0xffff0000u);
        const float xB0 = __uint_as_float(rwB << 16);
        const float xB1 = __uint_as_float(rwB & 0xffff0000u);
        float tA0 = xA0 + xr0 + fmaf(eA, wev.x, bev.x);
        float tA1 = xA1 + xr1 + fmaf(eA, wev.y, bev.y);
        float tB0 = xB0 + xr0 + fmaf(eB, wev.x, bev.x);
        float tB1 = xB1 + xr1 + fmaf(eB, wev.y, bev.y);
        tA0 = tA0 > 0.f ? tA0 : NEG_SLOPE * tA0;
        tA1 = tA1 > 0.f ? tA1 : NEG_SLOPE * tA1;
        tB0 = tB0 > 0.f ? tB0 : NEG_SLOPE * tB0;
        tB1 = tB1 > 0.f ? tB1 : NEG_SLOPE * tB1;
        float pA = fmaf(tA0, atv.x, tA1 * atv.y);
        float pB = fmaf(tB0, atv.x, tB1 * atv.y);
#pragma unroll
        for (int off = 1; off <= 16; off <<= 1) {
            pA += __shfl_xor(pA, off);
            pB += __shfl_xor(pB, off);
        }
        const float mnA = fmaxf(mA, pA);
        const float mnB = fmaxf(mB, pB);
        const float scA = __expf(mA - mnA), wA = __expf(pA - mnA);
        const float scB = __expf(mB - mnB), wB = __expf(pB - mnB);
        lA = fmaf(lA, scA, wA);
        lB = fmaf(lB, scB, wB);
        aA0 = fmaf(aA0, scA, wA * xA0);
        aA1 = fmaf(aA1, scA, wA * xA1);
        aB0 = fmaf(aB0, scB, wB * xB0);
        aB1 = fmaf(aB1, scB, wB * xB1);
        mA = mnA; mB = mnB;
    }
    if (i < end) {
        const int sA = ssrc[i];
        const float eA = sea[i];
        const unsigned rwA = xl[(long)sA * 64 + lane];
        const float xA0 = __uint_as_float(rwA << 16);
        const float xA1 = __uint_as_float(rwA & 0xffff0000u);
        float tA0 = xA0 + xr0 + fmaf(eA, wev.x, bev.x);
        float tA1 = xA1 + xr1 + fmaf(eA, wev.y, bev.y);
        tA0 = tA0 > 0.f ? tA0 : NEG_SLOPE * tA0;
        tA1 = tA1 > 0.f ? tA1 : NEG_SLOPE * tA1;
        float pA = fmaf(tA0, atv.x, tA1 * atv.y);
#pragma unroll
        for (int off = 1; off <= 16; off <<= 1) pA += __shfl_xor(pA, off);
        const float mnA = fmaxf(mA, pA);
        const float scA = __expf(mA - mnA), wA = __expf(pA - mnA);
        lA = fmaf(lA, scA, wA);
        aA0 = fmaf(aA0, scA, wA * xA0);
        aA1 = fmaf(aA1, scA, wA * xA1);
        mA = mnA;
    }
    // merge chains (guard -inf - -inf = nan for isolated nodes)
    const float mn = fmaxf(mA, mB);
    const float scA = (mA == -INFINITY) ? 0.f : __expf(mA - mn);
    const float scB = (mB == -INFINITY) ? 0.f : __expf(mB - mn);
    const float l  = lA * scA + lB * scB;
    const float a0 = aA0 * scA + aB0 * scB;
    const float a1 = aA1 * scA + aB1 * scB;
    const float inv = 1.f / fmaxf(l, 1e-20f);
    const float2 bsv = ldf2(bias, lane, isbf);
    float h0 = fmaf(a0, inv, bsv.x);
    float h1 = fmaf(a1, inv, bsv.y);
    h0 = h0 > 0.f ? h0 : expm1f(h0);
    h1 = h1 > 0.f ? h1 : expm1f(h1);
    // fused layer-2 linears: butterfly-reduce 2x5 dots over 128 channels
    float pl[5], pr[5];
#pragma unroll
    for (int c = 0; c < 5; c++) {
        pl[c] = h0 * ldf(W2l, (2 * lane) * 5 + c, isbf)
              + h1 * ldf(W2l, (2 * lane + 1) * 5 + c, isbf);
        pr[c] = h0 * ldf(W2r, (2 * lane) * 5 + c, isbf)
              + h1 * ldf(W2r, (2 * lane + 1) * 5 + c, isbf);
    }
#pragma unroll
    for (int off = 1; off <= 32; off <<= 1) {
#pragma unroll
        for (int c = 0; c < 5; c++) {
            pl[c] += __shfl_xor(pl[c], off);
            pr[c] += __shfl_xor(pr[c], off);
        }
    }
    if (lane == 0) {
#pragma unroll
        for (int c = 0; c < 5; c++) {
            xl2[(long)n * 5 + c] = pl[c] + ldf(b2l, c, isbf);
            xr2[(long)n * 5 + c] = pr[c] + ldf(b2r, c, isbf);
        }
    }
}

// Fused layer-2 attention: one wave per dst node, lane-per-edge chunks.
__global__ __launch_bounds__(256) void k_attn2(
    const unsigned* __restrict__ rp, const int* __restrict__ ssrc,
    const float* __restrict__ sea,
    const float* __restrict__ xl2, const float* __restrict__ xr2,
    const void* __restrict__ We, const void* __restrict__ be,
    const void* __restrict__ att, const void* __restrict__ bias,
    void* __restrict__ out, const int* __restrict__ flag) {
    const int isbf = flag[0];
    const int n = blockIdx.x * 4 + (threadIdx.x >> 6);
    if (n >= NN) return;
    const int lane = threadIdx.x & 63;
    float xrv[5], wev[5], bev[5], atv[5];
#pragma unroll
    for (int c = 0; c < 5; c++) {
        xrv[c] = xr2[(long)n * 5 + c];
        wev[c] = ldf(We, c, isbf);
        bev[c] = ldf(be, c, isbf);
        atv[c] = ldf(att, c, isbf);
    }
    float m = -INFINITY, l = 0.f, acc[5] = {0.f, 0.f, 0.f, 0.f, 0.f};
    const int beg = rp[n], end = rp[n + 1];
    for (int chunk = beg; chunk < end; chunk += 64) {
        const int idx = chunk + lane;
        const bool active = idx < end;
        float p = -INFINITY;
        float xls[5] = {0.f, 0.f, 0.f, 0.f, 0.f};
        if (active) {
            const int s = ssrc[idx];
            const float a = sea[idx];
            p = 0.f;
#pragma unroll
            for (int c = 0; c < 5; c++) {
                xls[c] = xl2[(long)s * 5 + c];
                float v = xls[c] + xrv[c] + fmaf(a, wev[c], bev[c]);
                v = v > 0.f ? v : NEG_SLOPE * v;
                p = fmaf(v, atv[c], p);
            }
        }
        float pm = p;
#pragma unroll
        for (int off = 1; off <= 32; off <<= 1) pm = fmaxf(pm, __shfl_xor(pm, off));
        const float mn = fmaxf(m, pm);
        const float sc = __expf(m - mn);
        float w = active ? __expf(p - mn) : 0.f;
        float sw = w;
        float sv[5];
#pragma unroll
        for (int c = 0; c < 5; c++) sv[c] = w * xls[c];
#pragma unroll
        for (int off = 1; off <= 32; off <<= 1) {
            sw += __shfl_xor(sw, off);
#pragma unroll
            for (int c = 0; c < 5; c++) sv[c] += __shfl_xor(sv[c], off);
        }
        l = fmaf(l, sc, sw);
#pragma unroll
        for (int c = 0; c < 5; c++) acc[c] = fmaf(acc[c], sc, sv[c]);
        m = mn;
    }
    if (lane == 0) {
        const float inv = 1.f / fmaxf(l, 1e-20f);
#pragma unroll
        for (int c = 0; c < 5; c++) {
            const float v = fmaf(acc[c], inv, ldf(bias, c, isbf));
            if (isbf) ((__hip_bfloat16*)out)[(long)n * 5 + c] = __float2bfloat16(v);
            else      ((float*)out)[(long)n * 5 + c] = v;
        }
    }
}

extern "C" void kernel_launch(void* const* d_in, const int* in_sizes, int n_in,
                              void* d_out, int out_size, void* d_ws, size_t ws_size,
                              hipStream_t stream) {
    const void* x    = d_in[0];
    const int*  ei   = (const int*)d_in[1];
    const void* ea   = d_in[2];
    const void* W1l  = d_in[3];
    const void* b1l  = d_in[4];
    const void* W1r  = d_in[5];
    const void* b1r  = d_in[6];
    const void* W1e  = d_in[7];
    const void* b1e  = d_in[8];
    const void* att1 = d_in[9];
    const void* bias1= d_in[10];
    const void* W2l  = d_in[11];
    const void* b2l  = d_in[12];
    const void* W2r  = d_in[13];
    const void* b2r  = d_in[14];
    const void* W2e  = d_in[15];
    const void* b2e  = d_in[16];
    const void* att2 = d_in[17];
    const void* bias2= d_in[18];

    float* W = (float*)d_ws;
    int*            flag    = (int*)W;
    unsigned*       row_ptr = (unsigned*)(W + 1000);
    unsigned*       cursor  = (unsigned*)(W + 60000);
    int*            ssrc    = (int*)(W + 120000);
    float*          sea     = W + 920000;
    unsigned short* xl1b    = (unsigned short*)(W + 1720000);
    unsigned short* xr1b    = (unsigned short*)(W + 4920000);
    unsigned short* bfrag   = (unsigned short*)(W + 8120000);
    float*          xl2     = W + 8200000;
    float*          xr2     = W + 8450000;

    k_sniff<<<1, 256, 0, stream>>>(x, flag);

    // CSR build (dst-sorted edges)
    k_init<<<(NN + 255) / 256, 256, 0, stream>>>(cursor, NN);
    k_hist<<<(NE + 255) / 256, 256, 0, stream>>>(ei, cursor);
    k_scan<<<1, 1024, 0, stream>>>(cursor, row_ptr);
    k_scatter<<<(NE + 255) / 256, 256, 0, stream>>>(ei, ea, cursor, ssrc, sea, flag);

    // Layer 1
    k_wprep<<<128, 256, 0, stream>>>(W1l, W1r, bfrag, flag);
    k_lin1<<<NN / 16, 256, 0, stream>>>(x, bfrag, b1l, b1r, xl1b, xr1b, flag);
    k_attn1<<<(NN + 3) / 4, 256, 0, stream>>>(row_ptr, ssrc, sea,
                                              (const unsigned*)xl1b, (const unsigned*)xr1b,
                                              W1e, b1e, att1, bias1,
                                              W2l, b2l, W2r, b2r, xl2, xr2, flag);
    // Layer 2
    k_attn2<<<(NN + 3) / 4, 256, 0, stream>>>(row_ptr, ssrc, sea, xl2, xr2,
                                              W2e, b2e, att2, bias2, d_out, flag);
}